// Round 9
// baseline (524.039 us; speedup 1.0000x reference)
//
#include <hip/hip_runtime.h>
#include <hip/hip_bf16.h>

// GAT 3-layer pipeline. fp32 I/O; bf16 MFMA interior.
// R16: agg_ln_k -> 2 parity WAVES per node (edges kbeg+2p+eo, stride 4/wave):
//      halves the serial gather chain and doubles wave concurrency; partials
//      combine via LDS + 1 barrier; wave0 runs LN epilogue. FMA block reverted
//      to R14 scalar form (R15's pk-f32x2 was ~flat-negative); att float2
//      interleave kept. denom/build unchanged from R15.

typedef __bf16 bf16x8_t __attribute__((ext_vector_type(8)));
typedef float  fx4      __attribute__((ext_vector_type(4)));

__device__ __forceinline__ float u2f(unsigned short u) {
    return __uint_as_float(((unsigned)u) << 16);
}
__device__ __forceinline__ unsigned short f2u(float f) {
    unsigned b = __float_as_uint(f);
    unsigned rounded = b + 0x7FFF + ((b >> 16) & 1);
    if (((b >> 23) & 0xFF) == 0xFF) rounded = b;
    return (unsigned short)(rounded >> 16);
}

// ---------------- fp32 -> bf16 bulk convert ----------------
__global__ void f32_to_bf16_k(const float* __restrict__ src, unsigned short* __restrict__ dst,
                              long n) {
    long i = (long)blockIdx.x * 256 + threadIdx.x;
    const long stride = (long)gridDim.x * 256;
    for (; i < n; i += stride) dst[i] = f2u(src[i]);
}

__global__ void transpose_conv_k(const float* __restrict__ W, unsigned short* __restrict__ Wt,
                                 int K, int N) {
    int idx = blockIdx.x * 256 + threadIdx.x;
    if (idx >= K * N) return;
    int k = idx / N, n = idx - k * N;
    Wt[(size_t)n * K + k] = f2u(W[idx]);
}

__global__ void fill_const_f32_k(float* __restrict__ out, long n, float v) {
    long i = (long)blockIdx.x * 256 + threadIdx.x;
    const long stride = (long)gridDim.x * 256;
    for (; i < n; i += stride) out[i] = v;
}

// ---------------- combined CSR(by row) + CSC(by col) build ----------------
// count + capture per-edge rank (atomic return). rank stored coalesced.
__global__ void count_both_k(const int* __restrict__ row, const int* __restrict__ col,
                             int* __restrict__ rcnt, int* __restrict__ ccnt,
                             int2* __restrict__ rank, int E, int Nn) {
    int e = blockIdx.x * 256 + threadIdx.x;
    if (e >= E) return;
    int r = row[e], c = col[e];
    int rr = -1, rc = -1;
    if ((unsigned)r < (unsigned)Nn) rr = atomicAdd(&rcnt[r], 1);
    if ((unsigned)c < (unsigned)Nn) rc = atomicAdd(&ccnt[c], 1);
    rank[e] = make_int2(rr, rc);
}

// ---- 3-pass device-wide inclusive scan over cnt2[0..2N) = [rcnt | ccnt] ----
__global__ __launch_bounds__(256) void scan1_k(const int* __restrict__ cnt,
                                               int* __restrict__ local,
                                               int* __restrict__ bsum, int n) {
    __shared__ int sm[256];
    int i = blockIdx.x * 256 + threadIdx.x;
    int tid = threadIdx.x;
    int v = (i < n) ? cnt[i] : 0;
    sm[tid] = v;
    __syncthreads();
    for (int o = 1; o < 256; o <<= 1) {
        int t = (tid >= o) ? sm[tid - o] : 0;
        __syncthreads();
        sm[tid] += t;
        __syncthreads();
    }
    if (i < n) local[i] = sm[tid];
    if (tid == 255) bsum[blockIdx.x] = sm[255];
}

__global__ __launch_bounds__(512) void scan2_k(int* __restrict__ bsum, int nb) {
    __shared__ int sm[512];
    int tid = threadIdx.x;
    int v = (tid < nb) ? bsum[tid] : 0;
    sm[tid] = v;
    __syncthreads();
    for (int o = 1; o < 512; o <<= 1) {
        int t = (tid >= o) ? sm[tid - o] : 0;
        __syncthreads();
        sm[tid] += t;
        __syncthreads();
    }
    if (tid < nb) bsum[tid] = sm[tid];
}

// pass 3: rowptr[i] (exclusive base at index i, inclusive at i+1) / colptr likewise.
__global__ __launch_bounds__(256) void scan3_k(const int* __restrict__ cnt,
                                               const int* __restrict__ local,
                                               const int* __restrict__ bsum,
                                               int* __restrict__ rowptr,
                                               int* __restrict__ colptr,
                                               int N) {
    int i = blockIdx.x * 256 + threadIdx.x;
    int n2 = 2 * N;
    if (i >= n2) return;
    int b = blockIdx.x;
    int s = local[i] + (b > 0 ? bsum[b - 1] : 0);
    if (i < N) {
        rowptr[i + 1] = s;
        if (i == 0) rowptr[0] = 0;
    } else {
        int bN = (N - 1) >> 8;
        int base = local[N - 1] + (bN > 0 ? bsum[bN - 1] : 0);   // broadcast loads
        int j = i - N;
        colptr[j + 1] = s - base;
        if (j == 0) colptr[0] = 0;
    }
}

// atomic-free scatter: slot = bucket base (L2-resident gather) + precomputed rank.
__global__ void fill_both_k(const int* __restrict__ row, const int* __restrict__ col,
                            const float* __restrict__ ew,
                            const int2* __restrict__ rank,
                            const int* __restrict__ rowptr, const int* __restrict__ colptr,
                            long* __restrict__ csr, long* __restrict__ csc,
                            int E, int Nn) {
    int e = blockIdx.x * 256 + threadIdx.x;
    if (e >= E) return;
    int r = row[e], c = col[e];
    int wb = __float_as_int(ew[e]);
    int2 rk = rank[e];
    if (rk.x >= 0) {
        int s = rowptr[r] + rk.x;
        int cc = ((unsigned)c < (unsigned)Nn) ? c : 0;
        long v = (long)(unsigned)cc | ((long)(unsigned)wb << 32);
        __builtin_nontemporal_store(v, csr + s);
    }
    if (rk.y >= 0) {
        int s = colptr[c] + rk.y;
        int rr = ((unsigned)r < (unsigned)Nn) ? r : 0;
        long v = (long)(unsigned)rr | ((long)(unsigned)wb << 32);
        __builtin_nontemporal_store(v, csc + s);
    }
}

// ---------------- bf16 MFMA GEMM: C[M,Ncol] = A[M,K] * Bt[Ncol,K]^T, bf16 out ----------------
#define LSTR 40
__global__ __launch_bounds__(256) void gemm_bf16(const unsigned short* __restrict__ A,
                                                 const unsigned short* __restrict__ Bt,
                                                 unsigned short* __restrict__ C,
                                                 int M, int Ncol, int K) {
    __shared__ unsigned short As[128 * LSTR];
    __shared__ unsigned short Bs[128 * LSTR];
    const int t = threadIdx.x;
    const int lane = t & 63;
    const int wave = t >> 6;
    const int quad = lane >> 4, l16 = lane & 15;
    const int row0 = blockIdx.y * 128, col0 = blockIdx.x * 128;
    const int wr = (wave >> 1) * 64, wc = (wave & 1) * 64;
    const int sr = t >> 2, ss = (t & 3) * 8;
    fx4 acc[4][4] = {};
    for (int k0 = 0; k0 < K; k0 += 32) {
#pragma unroll
        for (int rr = 0; rr < 2; rr++) {
            int r = sr + rr * 64;
            uint4 av = make_uint4(0, 0, 0, 0);
            int gr = row0 + r;
            if (gr < M) av = *(const uint4*)(A + (size_t)gr * K + k0 + ss);
            *(uint4*)(As + r * LSTR + ss) = av;
            uint4 bv = *(const uint4*)(Bt + (size_t)(col0 + r) * K + k0 + ss);
            *(uint4*)(Bs + r * LSTR + ss) = bv;
        }
        __syncthreads();
        bf16x8_t af[4], bfr[4];
#pragma unroll
        for (int i = 0; i < 4; i++) {
            af[i]  = *(const bf16x8_t*)(As + (wr + i * 16 + l16) * LSTR + quad * 8);
            bfr[i] = *(const bf16x8_t*)(Bs + (wc + i * 16 + l16) * LSTR + quad * 8);
        }
#pragma unroll
        for (int i = 0; i < 4; i++)
#pragma unroll
            for (int j = 0; j < 4; j++)
                acc[i][j] = __builtin_amdgcn_mfma_f32_16x16x32_bf16(af[i], bfr[j], acc[i][j], 0, 0, 0);
        __syncthreads();
    }
#pragma unroll
    for (int i = 0; i < 4; i++) {
        int rb = row0 + wr + i * 16 + quad * 4;
#pragma unroll
        for (int j = 0; j < 4; j++) {
            int c = col0 + wc + j * 16 + l16;
#pragma unroll
            for (int r = 0; r < 4; r++) {
                int gr = rb + r;
                if (gr < M) C[(size_t)gr * Ncol + c] = f2u(acc[i][j][r]);
            }
        }
    }
}

// ---------------- per-node attention scores (fp32 params, bf16 h) ----------------
template <int CPL, int LPH, int H>
__global__ __launch_bounds__(256) void scores_k(const unsigned short* __restrict__ hb,
                                                const float* __restrict__ asrc,
                                                const float* __restrict__ adst,
                                                float* __restrict__ ssrc, float* __restrict__ sdst,
                                                int N) {
    int node = blockIdx.x * 4 + (threadIdx.x >> 6);
    if (node >= N) return;
    int lane = threadIdx.x & 63;
    const int D = CPL * 64;
    const unsigned short* hp = hb + (size_t)node * D + lane * CPL;
    float s1 = 0.f, s2 = 0.f;
#pragma unroll
    for (int i = 0; i < CPL; i++) {
        float h = u2f(hp[i]);
        s1 += h * asrc[lane * CPL + i];
        s2 += h * adst[lane * CPL + i];
    }
#pragma unroll
    for (int m = 1; m < LPH; m <<= 1) {
        s1 += __shfl_xor(s1, m);
        s2 += __shfl_xor(s2, m);
    }
    if ((lane & (LPH - 1)) == 0) {
        ssrc[(size_t)node * H + lane / LPH] = s1;
        sdst[(size_t)node * H + lane / LPH] = s2;
    }
}

// ---------------- softmax denominator via CSC gather; emits packed att record ----------------
// att[node] = interleaved pairs { sd_0, rd_0, sd_1, rd_1, ... } (rd = 1/(denom+eps)).
// 2 parity threads per (node,head): stride-2 walks (chain /2), 3-deep pipeline,
// shfl_xor(H) combine. Grid covers N*2*H threads.
template <int H>
__global__ __launch_bounds__(256) void denom_csc_k(const int* __restrict__ colptr,
                                                   const int2* __restrict__ csc,
                                                   const float* __restrict__ ssrc,
                                                   const float* __restrict__ sdst,
                                                   float* __restrict__ att, int N) {
    int idx = blockIdx.x * 256 + threadIdx.x;
    const int L2H = (H == 4) ? 2 : ((H == 2) ? 1 : 0);
    int node = idx >> (L2H + 1);
    int rem = idx - (node << (L2H + 1));
    int h = rem & (H - 1);
    int parity = rem >> L2H;
    if (node >= N) return;
    const float sd = sdst[(size_t)node * H + h];
    float acc = 0.f;
    int kbeg = colptr[node], kend = colptr[node + 1];
    int k0 = kbeg + parity;
    if (k0 < kend) {
        int klast = kend - 1;
        int kB = k0 + 2, kC = k0 + 4;
        int2 ceA = csc[k0];
        int2 ceB = csc[kB < kend ? kB : klast];
        int2 ceC = csc[kC < kend ? kC : klast];
        float sA = ssrc[(size_t)ceA.x * H + h];
        float sB = ssrc[(size_t)ceB.x * H + h];
        for (int k = k0; k < kend; k += 2) {
            int kD = k + 6;
            int2 ceD = csc[kD < kend ? kD : klast];
            float sC = ssrc[(size_t)ceC.x * H + h];
            float we = __int_as_float(ceA.y);
            float s = sA + sd;
            s = (s > 0.f) ? s : 0.2f * s;                 // leaky_relu 0.2
            acc += __expf(fminf(s * we, 60.f));
            ceA = ceB; ceB = ceC; ceC = ceD;
            sA = sB; sB = sC;
        }
    }
    acc += __shfl_xor(acc, H);                            // combine parities
    if (parity == 0) {
        float2 pr;
        pr.x = sd;
        pr.y = 1.0f / (acc + 1e-16f);
        *(float2*)(att + (size_t)node * 2 * H + 2 * h) = pr;
    }
}

// ---------------- fused: CSR aggregate (recomputed alpha) + bias + LN + (ELU) ----------------
// 2 parity waves per node; each wave does 2 edges/iter (half-waves, eo), stride 4.
// Partials combine via LDS + 1 barrier; wave0 (parity 0) runs the LN epilogue.
// CPL = cols per lane over 32 lanes (D = 32*CPL). Index 3-deep, data 2-deep.
template <int CPL, int H, bool DOELU, bool F32OUT>
__global__ __launch_bounds__(256) void agg_ln_k(const unsigned short* __restrict__ hb,
                                                const float* __restrict__ ssrc,
                                                const float* __restrict__ att,
                                                const int* __restrict__ rowptr,
                                                const int2* __restrict__ csr,
                                                const float* __restrict__ bias,
                                                const float* __restrict__ gamma,
                                                const float* __restrict__ beta,
                                                void* __restrict__ outv, int N, int E) {
    __shared__ float sm[2][32][CPL];
    const int wid = threadIdx.x >> 6;
    const int nl = wid >> 1;            // node-local (0..1)
    const int parity = wid & 1;         // which parity wave of the node
    const int node = blockIdx.x * 2 + nl;
    const int lane = threadIdx.x & 63;
    const int hl = lane & 31;           // lane within half-wave (column group)
    const int eo = lane >> 5;           // which edge of the in-wave pair
    const int D = CPL * 32, C = D / H;
    const int colbase = hl * CPL;
    const int head = colbase / C;
    const bool valid = node < N;
    const unsigned short* hbl = hb + colbase;
    float accf[CPL] = {};
    float sn = 0.f;

    if (valid) {
        sn = ssrc[(size_t)node * H + head];
        int kbeg = rowptr[node], kend = rowptr[node + 1];
        if (kbeg < 0) kbeg = 0;
        if (kend > E) kend = E;
        int k0 = kbeg + 2 * parity;
        if (k0 < kend) {
            const int klast = kend - 1;
            int kA = k0 + eo, kB = k0 + 4 + eo, kC = k0 + 8 + eo;
            int2 ceA = csr[kA < kend ? kA : klast];
            int2 ceB = csr[kB < kend ? kB : klast];
            int2 ceC = csr[kC < kend ? kC : klast];
            float2 prA, prB;
            uint4 hvA = make_uint4(0,0,0,0), hvB = make_uint4(0,0,0,0);
            {
                prA = *(const float2*)(att + (size_t)ceA.x * (2 * H) + 2 * head);
                const unsigned short* hp = hbl + (size_t)ceA.x * D;
                if constexpr (CPL == 8) hvA = *(const uint4*)hp;
                else { uint2 t2 = *(const uint2*)hp; hvA.x = t2.x; hvA.y = t2.y; }
            }
            {
                prB = *(const float2*)(att + (size_t)ceB.x * (2 * H) + 2 * head);
                const unsigned short* hp = hbl + (size_t)ceB.x * D;
                if constexpr (CPL == 8) hvB = *(const uint4*)hp;
                else { uint2 t2 = *(const uint2*)hp; hvB.x = t2.x; hvB.y = t2.y; }
            }
            for (int k = k0; k < kend; k += 4) {
                int kD = k + 12 + eo;
                int2 ceD = csr[kD < kend ? kD : klast];
                float2 prC;
                uint4 hvC = make_uint4(0,0,0,0);
                {
                    prC = *(const float2*)(att + (size_t)ceC.x * (2 * H) + 2 * head);
                    const unsigned short* hp = hbl + (size_t)ceC.x * D;
                    if constexpr (CPL == 8) hvC = *(const uint4*)hp;
                    else { uint2 t2 = *(const uint2*)hp; hvC.x = t2.x; hvC.y = t2.y; }
                }
                // compute pair A (lane's half handles edge k+eo)
                float we = __int_as_float(ceA.y);
                float s = sn + prA.x;
                s = (s > 0.f) ? s : 0.2f * s;
                float ae = __expf(fminf(s * we, 60.f));   // bitwise-identical to denom term
                float w = ae * prA.y;
                w = (k + eo < kend) ? w : 0.f;            // mask invalid edge of tail pair
                accf[0] += w * u2f((unsigned short)(hvA.x & 0xFFFFu));
                accf[1] += w * u2f((unsigned short)(hvA.x >> 16));
                accf[2] += w * u2f((unsigned short)(hvA.y & 0xFFFFu));
                accf[3] += w * u2f((unsigned short)(hvA.y >> 16));
                if constexpr (CPL == 8) {
                    accf[4] += w * u2f((unsigned short)(hvA.z & 0xFFFFu));
                    accf[5] += w * u2f((unsigned short)(hvA.z >> 16));
                    accf[6] += w * u2f((unsigned short)(hvA.w & 0xFFFFu));
                    accf[7] += w * u2f((unsigned short)(hvA.w >> 16));
                }
                ceA = ceB; ceB = ceC; ceC = ceD;
                prA = prB; hvA = hvB;
                prB = prC; hvB = hvC;
            }
        }
    }
    // combine the two half-wave partials (both halves end with this wave's full sum)
#pragma unroll
    for (int i = 0; i < CPL; i++) accf[i] += __shfl_xor(accf[i], 32);

    // cross-wave (parity) combine via LDS
    if (parity == 1 && valid && lane < 32) {
#pragma unroll
        for (int i = 0; i < CPL; i++) sm[nl][lane][i] = accf[i];
    }
    __syncthreads();
    if (parity != 0 || !valid) return;
#pragma unroll
    for (int i = 0; i < CPL; i++) accf[i] += sm[nl][hl][i];

    float v[CPL];
    float sum = 0.f, sq = 0.f;
#pragma unroll
    for (int i = 0; i < CPL; i++) {
        v[i] = accf[i] + bias[colbase + i];
        sum += v[i];
        sq += v[i] * v[i];
    }
#pragma unroll
    for (int m = 1; m < 32; m <<= 1) {
        sum += __shfl_xor(sum, m);
        sq += __shfl_xor(sq, m);
    }
    float mu  = sum * (1.0f / D);
    float var = sq * (1.0f / D) - mu * mu;
    float inv = rsqrtf(fmaxf(var, 0.f) + 1e-5f);
    if (eo == 0) {
#pragma unroll
        for (int i = 0; i < CPL; i++) {
            float y = (v[i] - mu) * inv * gamma[colbase + i] + beta[colbase + i];
            if (DOELU) y = (y > 0.f) ? y : (__expf(y) - 1.f);
            size_t idx = (size_t)node * D + colbase + i;
            if constexpr (F32OUT) ((float*)outv)[idx] = y;
            else                  ((unsigned short*)outv)[idx] = f2u(y);
        }
    }
}

extern "C" void kernel_launch(void* const* d_in, const int* in_sizes, int n_in,
                              void* d_out, int out_size, void* d_ws, size_t ws_size,
                              hipStream_t stream) {
    const int IN_DIM = 384;
    const int N = in_sizes[0] / IN_DIM;
    const int E = in_sizes[1] / 2;
    float* outp = (float*)d_out;
    const int FG = 2048;

    if (n_in != 21 || out_size != N * 128) {
        fill_const_f32_k<<<FG, 256, 0, stream>>>(outp, (long)out_size, 9.0f);
        return;
    }

    const float* x = (const float*)d_in[0];
    const int* ei = (const int*)d_in[1];
    const int* row = ei;
    const int* col = ei + E;
    const float* ew = (const float*)d_in[2];
    const float* W1 = (const float*)d_in[3];
    const float* as1 = (const float*)d_in[4];
    const float* ad1 = (const float*)d_in[5];
    const float* b1 = (const float*)d_in[6];
    const float* g1 = (const float*)d_in[7];
    const float* be1 = (const float*)d_in[8];
    const float* W2 = (const float*)d_in[9];
    const float* as2 = (const float*)d_in[10];
    const float* ad2 = (const float*)d_in[11];
    const float* b2 = (const float*)d_in[12];
    const float* g2 = (const float*)d_in[13];
    const float* be2 = (const float*)d_in[14];
    const float* W3 = (const float*)d_in[15];
    const float* as3 = (const float*)d_in[16];
    const float* ad3 = (const float*)d_in[17];
    const float* b3 = (const float*)d_in[18];
    const float* g3 = (const float*)d_in[19];
    const float* be3 = (const float*)d_in[20];

    char* ws = (char*)d_ws;
    size_t off = 0;
    auto alloc = [&](size_t b) -> char* {
        char* p = ws + off;
        off = (off + b + 255) & ~(size_t)255;
        return p;
    };
    unsigned short* xb = (unsigned short*)alloc((size_t)N * IN_DIM * 2);
    unsigned short* hb = (unsigned short*)alloc((size_t)N * 256 * 2);
    unsigned short* ab = (unsigned short*)alloc((size_t)N * 256 * 2);
    float* att = (float*)alloc((size_t)N * 8 * 4);   // interleaved {sd_h, rd_h} pairs
    float* ssrc = (float*)alloc((size_t)N * 4 * 4);
    float* sdst = (float*)alloc((size_t)N * 4 * 4);
    unsigned short* W1t = (unsigned short*)alloc((size_t)384 * 256 * 2);
    unsigned short* W2t = (unsigned short*)alloc((size_t)256 * 256 * 2);
    unsigned short* W3t = (unsigned short*)alloc((size_t)256 * 128 * 2);
    int* rowptr = (int*)alloc((size_t)(N + 1) * 4);
    int* colptr = (int*)alloc((size_t)(N + 1) * 4);
    int* cnt2 = (int*)alloc((size_t)2 * N * 4);      // [rcnt | ccnt]
    int* slocal = (int*)alloc((size_t)2 * N * 4);    // scan pass-1 local results
    int* sbsum = (int*)alloc((size_t)512 * 4);       // scan block sums
    int2* rank = (int2*)alloc((size_t)E * 8);        // per-edge {rank_in_row, rank_in_col}
    long* csr = (long*)alloc((size_t)E * 8);         // CSR: {col, ew} per slot
    long* csc = (long*)alloc((size_t)E * 8);         // CSC: {row, ew} per slot

    if (off > ws_size) {
        fill_const_f32_k<<<FG, 256, 0, stream>>>(outp, (long)out_size, 7.0f);
        return;
    }

    int* rcnt = cnt2;
    int* ccnt = cnt2 + N;

    const int ebl = (E + 255) / 256;
    const int nbl4 = (N + 3) / 4;
    const int nbl2 = (N + 1) / 2;
    const int mrows = (N + 127) / 128;
    const int n2 = 2 * N;
    const int sblocks = (n2 + 255) / 256;            // 391 for N=50000 (<=512)

    // ---- input conversions ----
    f32_to_bf16_k<<<FG, 256, 0, stream>>>(x, xb, (long)N * IN_DIM);
    transpose_conv_k<<<(384 * 256 + 255) / 256, 256, 0, stream>>>(W1, W1t, 384, 256);
    transpose_conv_k<<<(256 * 256 + 255) / 256, 256, 0, stream>>>(W2, W2t, 256, 256);
    transpose_conv_k<<<(256 * 128 + 255) / 256, 256, 0, stream>>>(W3, W3t, 256, 128);

    // ---- CSR + CSC build (once, shared by all layers) ----
    hipMemsetAsync(cnt2, 0, (size_t)n2 * 4, stream);
    count_both_k<<<ebl, 256, 0, stream>>>(row, col, rcnt, ccnt, rank, E, N);
    scan1_k<<<sblocks, 256, 0, stream>>>(cnt2, slocal, sbsum, n2);
    scan2_k<<<1, 512, 0, stream>>>(sbsum, sblocks);
    scan3_k<<<sblocks, 256, 0, stream>>>(cnt2, slocal, sbsum, rowptr, colptr, N);
    fill_both_k<<<ebl, 256, 0, stream>>>(row, col, ew, rank, rowptr, colptr, csr, csc, E, N);

    // ---- layer 1: 384 -> 4x64 concat ----
    gemm_bf16<<<dim3(2, mrows), 256, 0, stream>>>(xb, W1t, hb, N, 256, 384);
    scores_k<4, 16, 4><<<nbl4, 256, 0, stream>>>(hb, as1, ad1, ssrc, sdst, N);
    denom_csc_k<4><<<(N * 8 + 255) / 256, 256, 0, stream>>>(colptr, (const int2*)csc, ssrc, sdst, att, N);
    agg_ln_k<8, 4, true, false><<<nbl2, 256, 0, stream>>>(hb, ssrc, att, rowptr, (const int2*)csr,
                                                          b1, g1, be1, ab, N, E);

    // ---- layer 2: 256 -> 4x64 concat ----
    gemm_bf16<<<dim3(2, mrows), 256, 0, stream>>>(ab, W2t, hb, N, 256, 256);
    scores_k<4, 16, 4><<<nbl4, 256, 0, stream>>>(hb, as2, ad2, ssrc, sdst, N);
    denom_csc_k<4><<<(N * 8 + 255) / 256, 256, 0, stream>>>(colptr, (const int2*)csc, ssrc, sdst, att, N);
    agg_ln_k<8, 4, true, false><<<nbl2, 256, 0, stream>>>(hb, ssrc, att, rowptr, (const int2*)csr,
                                                          b2, g2, be2, ab, N, E);

    // ---- layer 3: 256 -> 128, single head, final LN (no ELU), fp32 out ----
    gemm_bf16<<<dim3(1, mrows), 256, 0, stream>>>(ab, W3t, hb, N, 128, 256);
    scores_k<2, 64, 1><<<nbl4, 256, 0, stream>>>(hb, as3, ad3, ssrc, sdst, N);
    denom_csc_k<1><<<(N * 2 + 255) / 256, 256, 0, stream>>>(colptr, (const int2*)csc, ssrc, sdst, att, N);
    agg_ln_k<4, 1, false, true><<<nbl2, 256, 0, stream>>>(hb, ssrc, att, rowptr, (const int2*)csr,
                                                          b3, g3, be3, outp, N, E);
}

// Round 10
// 501.476 us; speedup vs baseline: 1.0450x; 1.0450x over previous
//
#include <hip/hip_runtime.h>
#include <hip/hip_bf16.h>

// GAT 3-layer pipeline. fp32 I/O; bf16 MFMA interior.
// R17: consolidate. agg_ln_k = R14 single-wave-per-node structure + att float2
//      interleave (scalar FMA body; R15's pk-f32x2 and R16's parity waves both
//      reverted -- agg is beyond-L2-service-bound at ~53us). scores for layers
//      1/2 folded into gemm epilogue (wave col-span == head span; shfl-tree
//      reduce, no atomics) -- removes 2 dispatches + 2x 25.6MB hb re-reads.
//      denom parity-split + rank-capture build unchanged.

typedef __bf16 bf16x8_t __attribute__((ext_vector_type(8)));
typedef float  fx4      __attribute__((ext_vector_type(4)));

__device__ __forceinline__ float u2f(unsigned short u) {
    return __uint_as_float(((unsigned)u) << 16);
}
__device__ __forceinline__ unsigned short f2u(float f) {
    unsigned b = __float_as_uint(f);
    unsigned rounded = b + 0x7FFF + ((b >> 16) & 1);
    if (((b >> 23) & 0xFF) == 0xFF) rounded = b;
    return (unsigned short)(rounded >> 16);
}

// ---------------- fp32 -> bf16 bulk convert ----------------
__global__ void f32_to_bf16_k(const float* __restrict__ src, unsigned short* __restrict__ dst,
                              long n) {
    long i = (long)blockIdx.x * 256 + threadIdx.x;
    const long stride = (long)gridDim.x * 256;
    for (; i < n; i += stride) dst[i] = f2u(src[i]);
}

__global__ void transpose_conv_k(const float* __restrict__ W, unsigned short* __restrict__ Wt,
                                 int K, int N) {
    int idx = blockIdx.x * 256 + threadIdx.x;
    if (idx >= K * N) return;
    int k = idx / N, n = idx - k * N;
    Wt[(size_t)n * K + k] = f2u(W[idx]);
}

__global__ void fill_const_f32_k(float* __restrict__ out, long n, float v) {
    long i = (long)blockIdx.x * 256 + threadIdx.x;
    const long stride = (long)gridDim.x * 256;
    for (; i < n; i += stride) out[i] = v;
}

// ---------------- combined CSR(by row) + CSC(by col) build ----------------
__global__ void count_both_k(const int* __restrict__ row, const int* __restrict__ col,
                             int* __restrict__ rcnt, int* __restrict__ ccnt,
                             int2* __restrict__ rank, int E, int Nn) {
    int e = blockIdx.x * 256 + threadIdx.x;
    if (e >= E) return;
    int r = row[e], c = col[e];
    int rr = -1, rc = -1;
    if ((unsigned)r < (unsigned)Nn) rr = atomicAdd(&rcnt[r], 1);
    if ((unsigned)c < (unsigned)Nn) rc = atomicAdd(&ccnt[c], 1);
    rank[e] = make_int2(rr, rc);
}

// ---- 3-pass device-wide inclusive scan over cnt2[0..2N) = [rcnt | ccnt] ----
__global__ __launch_bounds__(256) void scan1_k(const int* __restrict__ cnt,
                                               int* __restrict__ local,
                                               int* __restrict__ bsum, int n) {
    __shared__ int sm[256];
    int i = blockIdx.x * 256 + threadIdx.x;
    int tid = threadIdx.x;
    int v = (i < n) ? cnt[i] : 0;
    sm[tid] = v;
    __syncthreads();
    for (int o = 1; o < 256; o <<= 1) {
        int t = (tid >= o) ? sm[tid - o] : 0;
        __syncthreads();
        sm[tid] += t;
        __syncthreads();
    }
    if (i < n) local[i] = sm[tid];
    if (tid == 255) bsum[blockIdx.x] = sm[255];
}

__global__ __launch_bounds__(512) void scan2_k(int* __restrict__ bsum, int nb) {
    __shared__ int sm[512];
    int tid = threadIdx.x;
    int v = (tid < nb) ? bsum[tid] : 0;
    sm[tid] = v;
    __syncthreads();
    for (int o = 1; o < 512; o <<= 1) {
        int t = (tid >= o) ? sm[tid - o] : 0;
        __syncthreads();
        sm[tid] += t;
        __syncthreads();
    }
    if (tid < nb) bsum[tid] = sm[tid];
}

__global__ __launch_bounds__(256) void scan3_k(const int* __restrict__ cnt,
                                               const int* __restrict__ local,
                                               const int* __restrict__ bsum,
                                               int* __restrict__ rowptr,
                                               int* __restrict__ colptr,
                                               int N) {
    int i = blockIdx.x * 256 + threadIdx.x;
    int n2 = 2 * N;
    if (i >= n2) return;
    int b = blockIdx.x;
    int s = local[i] + (b > 0 ? bsum[b - 1] : 0);
    if (i < N) {
        rowptr[i + 1] = s;
        if (i == 0) rowptr[0] = 0;
    } else {
        int bN = (N - 1) >> 8;
        int base = local[N - 1] + (bN > 0 ? bsum[bN - 1] : 0);   // broadcast loads
        int j = i - N;
        colptr[j + 1] = s - base;
        if (j == 0) colptr[0] = 0;
    }
}

// atomic-free scatter: slot = bucket base (L2-resident gather) + precomputed rank.
__global__ void fill_both_k(const int* __restrict__ row, const int* __restrict__ col,
                            const float* __restrict__ ew,
                            const int2* __restrict__ rank,
                            const int* __restrict__ rowptr, const int* __restrict__ colptr,
                            long* __restrict__ csr, long* __restrict__ csc,
                            int E, int Nn) {
    int e = blockIdx.x * 256 + threadIdx.x;
    if (e >= E) return;
    int r = row[e], c = col[e];
    int wb = __float_as_int(ew[e]);
    int2 rk = rank[e];
    if (rk.x >= 0) {
        int s = rowptr[r] + rk.x;
        int cc = ((unsigned)c < (unsigned)Nn) ? c : 0;
        long v = (long)(unsigned)cc | ((long)(unsigned)wb << 32);
        __builtin_nontemporal_store(v, csr + s);
    }
    if (rk.y >= 0) {
        int s = colptr[c] + rk.y;
        int rr = ((unsigned)r < (unsigned)Nn) ? r : 0;
        long v = (long)(unsigned)rr | ((long)(unsigned)wb << 32);
        __builtin_nontemporal_store(v, csc + s);
    }
}

// ---------------- bf16 MFMA GEMM: C[M,Ncol] = A[M,K] * Bt[Ncol,K]^T, bf16 out ----------------
// FSC: fuse per-node attention scores into epilogue (requires Ncol=256, H=4:
// each wave's 64-col span == one head; 16-lane shfl tree reduce, no atomics).
#define LSTR 40
template <bool FSC>
__global__ __launch_bounds__(256) void gemm_bf16(const unsigned short* __restrict__ A,
                                                 const unsigned short* __restrict__ Bt,
                                                 unsigned short* __restrict__ C,
                                                 int M, int Ncol, int K,
                                                 const float* __restrict__ asrc,
                                                 const float* __restrict__ adst,
                                                 float* __restrict__ ssrc,
                                                 float* __restrict__ sdst) {
    __shared__ unsigned short As[128 * LSTR];
    __shared__ unsigned short Bs[128 * LSTR];
    const int t = threadIdx.x;
    const int lane = t & 63;
    const int wave = t >> 6;
    const int quad = lane >> 4, l16 = lane & 15;
    const int row0 = blockIdx.y * 128, col0 = blockIdx.x * 128;
    const int wr = (wave >> 1) * 64, wc = (wave & 1) * 64;
    const int sr = t >> 2, ss = (t & 3) * 8;
    fx4 acc[4][4] = {};
    for (int k0 = 0; k0 < K; k0 += 32) {
#pragma unroll
        for (int rr = 0; rr < 2; rr++) {
            int r = sr + rr * 64;
            uint4 av = make_uint4(0, 0, 0, 0);
            int gr = row0 + r;
            if (gr < M) av = *(const uint4*)(A + (size_t)gr * K + k0 + ss);
            *(uint4*)(As + r * LSTR + ss) = av;
            uint4 bv = *(const uint4*)(Bt + (size_t)(col0 + r) * K + k0 + ss);
            *(uint4*)(Bs + r * LSTR + ss) = bv;
        }
        __syncthreads();
        bf16x8_t af[4], bfr[4];
#pragma unroll
        for (int i = 0; i < 4; i++) {
            af[i]  = *(const bf16x8_t*)(As + (wr + i * 16 + l16) * LSTR + quad * 8);
            bfr[i] = *(const bf16x8_t*)(Bs + (wc + i * 16 + l16) * LSTR + quad * 8);
        }
#pragma unroll
        for (int i = 0; i < 4; i++)
#pragma unroll
            for (int j = 0; j < 4; j++)
                acc[i][j] = __builtin_amdgcn_mfma_f32_16x16x32_bf16(af[i], bfr[j], acc[i][j], 0, 0, 0);
        __syncthreads();
    }
#pragma unroll
    for (int i = 0; i < 4; i++) {
        int rb = row0 + wr + i * 16 + quad * 4;
#pragma unroll
        for (int j = 0; j < 4; j++) {
            int c = col0 + wc + j * 16 + l16;
#pragma unroll
            for (int r = 0; r < 4; r++) {
                int gr = rb + r;
                if (gr < M) C[(size_t)gr * Ncol + c] = f2u(acc[i][j][r]);
            }
        }
    }
    if constexpr (FSC) {
        // head for this wave: block x covers cols [128bx,128bx+128) = heads {2bx, 2bx+1}
        const int head = blockIdx.x * 2 + (wave & 1);
        const float a1 = asrc[head * 64 + 0 * 16 + l16];
        const float a2 = asrc[head * 64 + 1 * 16 + l16];
        const float a3 = asrc[head * 64 + 2 * 16 + l16];
        const float a4 = asrc[head * 64 + 3 * 16 + l16];
        const float b1 = adst[head * 64 + 0 * 16 + l16];
        const float b2 = adst[head * 64 + 1 * 16 + l16];
        const float b3 = adst[head * 64 + 2 * 16 + l16];
        const float b4 = adst[head * 64 + 3 * 16 + l16];
#pragma unroll
        for (int i = 0; i < 4; i++) {
#pragma unroll
            for (int r = 0; r < 4; r++) {
                float s1 = acc[i][0][r] * a1 + acc[i][1][r] * a2 + acc[i][2][r] * a3 + acc[i][3][r] * a4;
                float s2 = acc[i][0][r] * b1 + acc[i][1][r] * b2 + acc[i][2][r] * b3 + acc[i][3][r] * b4;
#pragma unroll
                for (int m = 1; m < 16; m <<= 1) {
                    s1 += __shfl_xor(s1, m);
                    s2 += __shfl_xor(s2, m);
                }
                int grow = row0 + wr + i * 16 + quad * 4 + r;
                if (l16 == 0 && grow < M) {
                    ssrc[(size_t)grow * 4 + head] = s1;
                    sdst[(size_t)grow * 4 + head] = s2;
                }
            }
        }
    }
}

// ---------------- per-node attention scores (fp32 params, bf16 h) ----------------
template <int CPL, int LPH, int H>
__global__ __launch_bounds__(256) void scores_k(const unsigned short* __restrict__ hb,
                                                const float* __restrict__ asrc,
                                                const float* __restrict__ adst,
                                                float* __restrict__ ssrc, float* __restrict__ sdst,
                                                int N) {
    int node = blockIdx.x * 4 + (threadIdx.x >> 6);
    if (node >= N) return;
    int lane = threadIdx.x & 63;
    const int D = CPL * 64;
    const unsigned short* hp = hb + (size_t)node * D + lane * CPL;
    float s1 = 0.f, s2 = 0.f;
#pragma unroll
    for (int i = 0; i < CPL; i++) {
        float h = u2f(hp[i]);
        s1 += h * asrc[lane * CPL + i];
        s2 += h * adst[lane * CPL + i];
    }
#pragma unroll
    for (int m = 1; m < LPH; m <<= 1) {
        s1 += __shfl_xor(s1, m);
        s2 += __shfl_xor(s2, m);
    }
    if ((lane & (LPH - 1)) == 0) {
        ssrc[(size_t)node * H + lane / LPH] = s1;
        sdst[(size_t)node * H + lane / LPH] = s2;
    }
}

// ---------------- softmax denominator via CSC gather; emits packed att record ----------------
// att[node] = interleaved pairs { sd_0, rd_0, sd_1, rd_1, ... } (rd = 1/(denom+eps)).
// 2 parity threads per (node,head): stride-2 walks, 3-deep pipeline, shfl combine.
template <int H>
__global__ __launch_bounds__(256) void denom_csc_k(const int* __restrict__ colptr,
                                                   const int2* __restrict__ csc,
                                                   const float* __restrict__ ssrc,
                                                   const float* __restrict__ sdst,
                                                   float* __restrict__ att, int N) {
    int idx = blockIdx.x * 256 + threadIdx.x;
    const int L2H = (H == 4) ? 2 : ((H == 2) ? 1 : 0);
    int node = idx >> (L2H + 1);
    int rem = idx - (node << (L2H + 1));
    int h = rem & (H - 1);
    int parity = rem >> L2H;
    if (node >= N) return;
    const float sd = sdst[(size_t)node * H + h];
    float acc = 0.f;
    int kbeg = colptr[node], kend = colptr[node + 1];
    int k0 = kbeg + parity;
    if (k0 < kend) {
        int klast = kend - 1;
        int kB = k0 + 2, kC = k0 + 4;
        int2 ceA = csc[k0];
        int2 ceB = csc[kB < kend ? kB : klast];
        int2 ceC = csc[kC < kend ? kC : klast];
        float sA = ssrc[(size_t)ceA.x * H + h];
        float sB = ssrc[(size_t)ceB.x * H + h];
        for (int k = k0; k < kend; k += 2) {
            int kD = k + 6;
            int2 ceD = csc[kD < kend ? kD : klast];
            float sC = ssrc[(size_t)ceC.x * H + h];
            float we = __int_as_float(ceA.y);
            float s = sA + sd;
            s = (s > 0.f) ? s : 0.2f * s;                 // leaky_relu 0.2
            acc += __expf(fminf(s * we, 60.f));
            ceA = ceB; ceB = ceC; ceC = ceD;
            sA = sB; sB = sC;
        }
    }
    acc += __shfl_xor(acc, H);                            // combine parities
    if (parity == 0) {
        float2 pr;
        pr.x = sd;
        pr.y = 1.0f / (acc + 1e-16f);
        *(float2*)(att + (size_t)node * 2 * H + 2 * h) = pr;
    }
}

// ---------------- fused: CSR aggregate (recomputed alpha) + bias + LN + (ELU) ----------------
// 2 edges per wave-iteration: lanes 0-31 handle edge k, lanes 32-63 edge k+1.
// CPL = cols per lane over 32 lanes (D = 32*CPL). Index 3-deep, data 2-deep.
// att read = single float2 (interleaved layout); scalar FMA body.
template <int CPL, int H, bool DOELU, bool F32OUT>
__global__ __launch_bounds__(256) void agg_ln_k(const unsigned short* __restrict__ hb,
                                                const float* __restrict__ ssrc,
                                                const float* __restrict__ att,
                                                const int* __restrict__ rowptr,
                                                const int2* __restrict__ csr,
                                                const float* __restrict__ bias,
                                                const float* __restrict__ gamma,
                                                const float* __restrict__ beta,
                                                void* __restrict__ outv, int N, int E) {
    int node = blockIdx.x * 4 + (threadIdx.x >> 6);
    if (node >= N) return;
    const int lane = threadIdx.x & 63;
    const int hl = lane & 31;           // lane within half-wave
    const int eo = lane >> 5;           // which edge of the pair
    const int D = CPL * 32, C = D / H;
    const int colbase = hl * CPL;
    const int head = colbase / C;
    const float sn = ssrc[(size_t)node * H + head];
    const unsigned short* hbl = hb + colbase;
    float accf[CPL] = {};
    int kbeg = rowptr[node], kend = rowptr[node + 1];
    if (kbeg < 0) kbeg = 0;
    if (kend > E) kend = E;

    if (kbeg < kend) {
        const int klast = kend - 1;
        int kA = kbeg + eo, kB = kbeg + 2 + eo, kC = kbeg + 4 + eo;
        int2 ceA = csr[kA < kend ? kA : klast];
        int2 ceB = csr[kB < kend ? kB : klast];
        int2 ceC = csr[kC < kend ? kC : klast];
        float2 prA, prB;
        uint4 hvA = make_uint4(0,0,0,0), hvB = make_uint4(0,0,0,0);
        {
            prA = *(const float2*)(att + (size_t)ceA.x * (2 * H) + 2 * head);
            const unsigned short* hp = hbl + (size_t)ceA.x * D;
            if constexpr (CPL == 8) hvA = *(const uint4*)hp;
            else { uint2 t2 = *(const uint2*)hp; hvA.x = t2.x; hvA.y = t2.y; }
        }
        {
            prB = *(const float2*)(att + (size_t)ceB.x * (2 * H) + 2 * head);
            const unsigned short* hp = hbl + (size_t)ceB.x * D;
            if constexpr (CPL == 8) hvB = *(const uint4*)hp;
            else { uint2 t2 = *(const uint2*)hp; hvB.x = t2.x; hvB.y = t2.y; }
        }
        for (int k = kbeg; k < kend; k += 2) {
            int kD = k + 6 + eo;
            int2 ceD = csr[kD < kend ? kD : klast];
            float2 prC;
            uint4 hvC = make_uint4(0,0,0,0);
            {
                prC = *(const float2*)(att + (size_t)ceC.x * (2 * H) + 2 * head);
                const unsigned short* hp = hbl + (size_t)ceC.x * D;
                if constexpr (CPL == 8) hvC = *(const uint4*)hp;
                else { uint2 t2 = *(const uint2*)hp; hvC.x = t2.x; hvC.y = t2.y; }
            }
            // compute pair A (lane's half handles edge k+eo)
            float we = __int_as_float(ceA.y);
            float s = sn + prA.x;
            s = (s > 0.f) ? s : 0.2f * s;
            float ae = __expf(fminf(s * we, 60.f));   // bitwise-identical to denom term
            float w = ae * prA.y;
            w = (k + eo < kend) ? w : 0.f;            // mask invalid second edge of tail pair
            accf[0] += w * u2f((unsigned short)(hvA.x & 0xFFFFu));
            accf[1] += w * u2f((unsigned short)(hvA.x >> 16));
            accf[2] += w * u2f((unsigned short)(hvA.y & 0xFFFFu));
            accf[3] += w * u2f((unsigned short)(hvA.y >> 16));
            if constexpr (CPL == 8) {
                accf[4] += w * u2f((unsigned short)(hvA.z & 0xFFFFu));
                accf[5] += w * u2f((unsigned short)(hvA.z >> 16));
                accf[6] += w * u2f((unsigned short)(hvA.w & 0xFFFFu));
                accf[7] += w * u2f((unsigned short)(hvA.w >> 16));
            }
            ceA = ceB; ceB = ceC; ceC = ceD;
            prA = prB; hvA = hvB;
            prB = prC; hvB = hvC;
        }
    }
    // combine the two half-wave partial sums (both halves end with full sums)
#pragma unroll
    for (int i = 0; i < CPL; i++) accf[i] += __shfl_xor(accf[i], 32);

    float v[CPL];
    float sum = 0.f, sq = 0.f;
#pragma unroll
    for (int i = 0; i < CPL; i++) {
        v[i] = accf[i] + bias[colbase + i];
        sum += v[i];
        sq += v[i] * v[i];
    }
#pragma unroll
    for (int m = 1; m < 32; m <<= 1) {
        sum += __shfl_xor(sum, m);
        sq += __shfl_xor(sq, m);
    }
    float mu  = sum * (1.0f / D);
    float var = sq * (1.0f / D) - mu * mu;
    float inv = rsqrtf(fmaxf(var, 0.f) + 1e-5f);
    if (eo == 0) {
#pragma unroll
        for (int i = 0; i < CPL; i++) {
            float y = (v[i] - mu) * inv * gamma[colbase + i] + beta[colbase + i];
            if (DOELU) y = (y > 0.f) ? y : (__expf(y) - 1.f);
            size_t idx = (size_t)node * D + colbase + i;
            if constexpr (F32OUT) ((float*)outv)[idx] = y;
            else                  ((unsigned short*)outv)[idx] = f2u(y);
        }
    }
}

extern "C" void kernel_launch(void* const* d_in, const int* in_sizes, int n_in,
                              void* d_out, int out_size, void* d_ws, size_t ws_size,
                              hipStream_t stream) {
    const int IN_DIM = 384;
    const int N = in_sizes[0] / IN_DIM;
    const int E = in_sizes[1] / 2;
    float* outp = (float*)d_out;
    const int FG = 2048;

    if (n_in != 21 || out_size != N * 128) {
        fill_const_f32_k<<<FG, 256, 0, stream>>>(outp, (long)out_size, 9.0f);
        return;
    }

    const float* x = (const float*)d_in[0];
    const int* ei = (const int*)d_in[1];
    const int* row = ei;
    const int* col = ei + E;
    const float* ew = (const float*)d_in[2];
    const float* W1 = (const float*)d_in[3];
    const float* as1 = (const float*)d_in[4];
    const float* ad1 = (const float*)d_in[5];
    const float* b1 = (const float*)d_in[6];
    const float* g1 = (const float*)d_in[7];
    const float* be1 = (const float*)d_in[8];
    const float* W2 = (const float*)d_in[9];
    const float* as2 = (const float*)d_in[10];
    const float* ad2 = (const float*)d_in[11];
    const float* b2 = (const float*)d_in[12];
    const float* g2 = (const float*)d_in[13];
    const float* be2 = (const float*)d_in[14];
    const float* W3 = (const float*)d_in[15];
    const float* as3 = (const float*)d_in[16];
    const float* ad3 = (const float*)d_in[17];
    const float* b3 = (const float*)d_in[18];
    const float* g3 = (const float*)d_in[19];
    const float* be3 = (const float*)d_in[20];

    char* ws = (char*)d_ws;
    size_t off = 0;
    auto alloc = [&](size_t b) -> char* {
        char* p = ws + off;
        off = (off + b + 255) & ~(size_t)255;
        return p;
    };
    unsigned short* xb = (unsigned short*)alloc((size_t)N * IN_DIM * 2);
    unsigned short* hb = (unsigned short*)alloc((size_t)N * 256 * 2);
    unsigned short* ab = (unsigned short*)alloc((size_t)N * 256 * 2);
    float* att = (float*)alloc((size_t)N * 8 * 4);   // interleaved {sd_h, rd_h} pairs
    float* ssrc = (float*)alloc((size_t)N * 4 * 4);
    float* sdst = (float*)alloc((size_t)N * 4 * 4);
    unsigned short* W1t = (unsigned short*)alloc((size_t)384 * 256 * 2);
    unsigned short* W2t = (unsigned short*)alloc((size_t)256 * 256 * 2);
    unsigned short* W3t = (unsigned short*)alloc((size_t)256 * 128 * 2);
    int* rowptr = (int*)alloc((size_t)(N + 1) * 4);
    int* colptr = (int*)alloc((size_t)(N + 1) * 4);
    int* cnt2 = (int*)alloc((size_t)2 * N * 4);      // [rcnt | ccnt]
    int* slocal = (int*)alloc((size_t)2 * N * 4);    // scan pass-1 local results
    int* sbsum = (int*)alloc((size_t)512 * 4);       // scan block sums
    int2* rank = (int2*)alloc((size_t)E * 8);        // per-edge {rank_in_row, rank_in_col}
    long* csr = (long*)alloc((size_t)E * 8);         // CSR: {col, ew} per slot
    long* csc = (long*)alloc((size_t)E * 8);         // CSC: {row, ew} per slot

    if (off > ws_size) {
        fill_const_f32_k<<<FG, 256, 0, stream>>>(outp, (long)out_size, 7.0f);
        return;
    }

    int* rcnt = cnt2;
    int* ccnt = cnt2 + N;

    const int ebl = (E + 255) / 256;
    const int nbl4 = (N + 3) / 4;
    const int mrows = (N + 127) / 128;
    const int n2 = 2 * N;
    const int sblocks = (n2 + 255) / 256;            // 391 for N=50000 (<=512)

    // ---- input conversions ----
    f32_to_bf16_k<<<FG, 256, 0, stream>>>(x, xb, (long)N * IN_DIM);
    transpose_conv_k<<<(384 * 256 + 255) / 256, 256, 0, stream>>>(W1, W1t, 384, 256);
    transpose_conv_k<<<(256 * 256 + 255) / 256, 256, 0, stream>>>(W2, W2t, 256, 256);
    transpose_conv_k<<<(256 * 128 + 255) / 256, 256, 0, stream>>>(W3, W3t, 256, 128);

    // ---- CSR + CSC build (once, shared by all layers) ----
    hipMemsetAsync(cnt2, 0, (size_t)n2 * 4, stream);
    count_both_k<<<ebl, 256, 0, stream>>>(row, col, rcnt, ccnt, rank, E, N);
    scan1_k<<<sblocks, 256, 0, stream>>>(cnt2, slocal, sbsum, n2);
    scan2_k<<<1, 512, 0, stream>>>(sbsum, sblocks);
    scan3_k<<<sblocks, 256, 0, stream>>>(cnt2, slocal, sbsum, rowptr, colptr, N);
    fill_both_k<<<ebl, 256, 0, stream>>>(row, col, ew, rank, rowptr, colptr, csr, csc, E, N);

    // ---- layer 1: 384 -> 4x64 concat (scores fused into gemm epilogue) ----
    gemm_bf16<true><<<dim3(2, mrows), 256, 0, stream>>>(xb, W1t, hb, N, 256, 384,
                                                        as1, ad1, ssrc, sdst);
    denom_csc_k<4><<<(N * 8 + 255) / 256, 256, 0, stream>>>(colptr, (const int2*)csc, ssrc, sdst, att, N);
    agg_ln_k<8, 4, true, false><<<nbl4, 256, 0, stream>>>(hb, ssrc, att, rowptr, (const int2*)csr,
                                                          b1, g1, be1, ab, N, E);

    // ---- layer 2: 256 -> 4x64 concat (scores fused into gemm epilogue) ----
    gemm_bf16<true><<<dim3(2, mrows), 256, 0, stream>>>(ab, W2t, hb, N, 256, 256,
                                                        as2, ad2, ssrc, sdst);
    denom_csc_k<4><<<(N * 8 + 255) / 256, 256, 0, stream>>>(colptr, (const int2*)csc, ssrc, sdst, att, N);
    agg_ln_k<8, 4, true, false><<<nbl4, 256, 0, stream>>>(hb, ssrc, att, rowptr, (const int2*)csr,
                                                          b2, g2, be2, ab, N, E);

    // ---- layer 3: 256 -> 128, single head, final LN (no ELU), fp32 out ----
    gemm_bf16<false><<<dim3(1, mrows), 256, 0, stream>>>(ab, W3t, hb, N, 128, 256,
                                                         nullptr, nullptr, nullptr, nullptr);
    scores_k<2, 64, 1><<<nbl4, 256, 0, stream>>>(hb, as3, ad3, ssrc, sdst, N);
    denom_csc_k<1><<<(N * 2 + 255) / 256, 256, 0, stream>>>(colptr, (const int2*)csc, ssrc, sdst, att, N);
    agg_ln_k<4, 1, false, true><<<nbl4, 256, 0, stream>>>(hb, ssrc, att, rowptr, (const int2*)csr,
                                                          b3, g3, be3, outp, N, E);
}